// Round 4
// baseline (255.810 us; speedup 1.0000x reference)
//
#include <hip/hip_runtime.h>

// Dims (fixed): S=4096, N=32, E=512, H=8, DK=64. Query pos l = 2048 (L==1).
// qb = q.bk cancels in softmax (constant over s) -> dropped everywhere.
#define SS 4096
#define NB 32
#define EE 512
#define HH 8
#define DKK 64
#define LQ 2048
#define NCHUNK 16          // s-chunks per n in fused kernel (256 s each)

__device__ __forceinline__ constexpr int bitrev3(int x) {
  return ((x & 1) << 2) | (x & 2) | ((x & 4) >> 2);
}

// ---- K1: q[n,h,:] then qk[n,h,e] = sum_d q_d * Wk[h*64+d, e] ---------------
__global__ __launch_bounds__(256) void k_qproj(const float* __restrict__ src,
                                               const float* __restrict__ Wq,
                                               const float* __restrict__ bq,
                                               const float* __restrict__ Wk,
                                               float* __restrict__ qk) {
  __shared__ float qd[DKK];
  int n = blockIdx.x >> 3, h = blockIdx.x & 7;
  int tid = threadIdx.x;
  int d = tid >> 2, part = tid & 3;
  const float4* xs = (const float4*)(src + ((size_t)LQ * NB + n) * EE);
  const float4* wr = (const float4*)(Wq + (size_t)(h * DKK + d) * EE);
  float acc = 0.f;
#pragma unroll 8
  for (int i = 0; i < 32; ++i) {
    float4 a = xs[part * 32 + i], b = wr[part * 32 + i];
    acc = fmaf(a.x, b.x, fmaf(a.y, b.y, fmaf(a.z, b.z, fmaf(a.w, b.w, acc))));
  }
  acc += __shfl_xor(acc, 1, 64);
  acc += __shfl_xor(acc, 2, 64);
  if (part == 0) qd[d] = acc + bq[h * DKK + d];
  __syncthreads();
  float a0 = 0.f, a1 = 0.f;
#pragma unroll 8
  for (int d2 = 0; d2 < DKK; ++d2) {
    float qv = qd[d2];
    const float* row = Wk + (size_t)(h * DKK + d2) * EE;
    a0 = fmaf(qv, row[tid], a0);
    a1 = fmaf(qv, row[tid + 256], a1);
  }
  size_t base = (size_t)(n * HH + h) * EE;
  qk[base + tid] = a0;
  qk[base + tid + 256] = a1;
}

// ---- K2 (fused): one pass over src; 2 rows per wave-iter (ILP).
// Slot mapping for the dot: lane L, slot j <-> head bitrev3((L&7)^j).
// Fold reduce (10 DS) -> lane L holds full dot for head bitrev3(L&7).
// exp -> weights are wave-uniform -> v_readlane into SGPRs (no gather DS).
// Accumulator is head-major with SGPR weight operands.
__global__ __launch_bounds__(256, 2) void k_fused(const float* __restrict__ src,
                                                  const float* __restrict__ qk,
                                                  float* __restrict__ part,
                                                  float* __restrict__ lw) {
  __shared__ float cbuf[HH * EE];   // 16 KB
  __shared__ float lbuf[4 * HH];
  int b = blockIdx.x;
  int n = b >> 4, c = b & 15;
  int tid = threadIdx.x, wave = tid >> 6, lane = tid & 63;

  // qk fragments in slot order (per-lane head mapping, dot only)
  const float4* qk4 = (const float4*)qk;
  float4 qf[16];
#pragma unroll
  for (int j = 0; j < HH; ++j) {
    int hj = bitrev3((lane ^ j) & 7);
    int qbase = (n * HH + hj) * (EE / 4);
    qf[2 * j] = qk4[qbase + lane];
    qf[2 * j + 1] = qk4[qbase + 64 + lane];
  }

  float4 acc[16];   // head-major: acc[2h], acc[2h+1]
#pragma unroll
  for (int i = 0; i < 16; ++i) acc[i] = make_float4(0.f, 0.f, 0.f, 0.f);
  float lp = 0.f;

  // rows: rA = c*256 + it*8 + wave*2, rB = rA+1, it = 0..31
  const size_t rowstep = (size_t)NB * (EE / 4);   // float4 step for s+1
  const float4* sp = (const float4*)src +
                     ((size_t)((c << 8) + wave * 2) * NB + n) * (EE / 4);
  float4 nA0 = sp[lane], nA1 = sp[64 + lane];
  float4 nB0 = sp[rowstep + lane], nB1 = sp[rowstep + 64 + lane];

  for (int it = 0; it < 32; ++it) {
    float4 aA = nA0, dA = nA1, aB = nB0, dB = nB1;
    if (it < 31) {
      sp += 8 * rowstep;
      nA0 = sp[lane]; nA1 = sp[64 + lane];
      nB0 = sp[rowstep + lane]; nB1 = sp[rowstep + 64 + lane];
    }
    float pA[8], pB[8];
#pragma unroll
    for (int j = 0; j < HH; ++j) {
      float4 u = qf[2 * j], v = qf[2 * j + 1];
      pA[j] = fmaf(aA.x, u.x, fmaf(aA.y, u.y, fmaf(aA.z, u.z, fmaf(aA.w, u.w,
              fmaf(dA.x, v.x, fmaf(dA.y, v.y, fmaf(dA.z, v.z, dA.w * v.w)))))));
      pB[j] = fmaf(aB.x, u.x, fmaf(aB.y, u.y, fmaf(aB.z, u.z, fmaf(aB.w, u.w,
              fmaf(dB.x, v.x, fmaf(dB.y, v.y, fmaf(dB.z, v.z, dB.w * v.w)))))));
    }
    // two independent fold-reductions (compiler interleaves the chains)
    pA[0] += __shfl_xor(pA[1], 1, 64);
    pB[0] += __shfl_xor(pB[1], 1, 64);
    pA[2] += __shfl_xor(pA[3], 1, 64);
    pB[2] += __shfl_xor(pB[3], 1, 64);
    pA[4] += __shfl_xor(pA[5], 1, 64);
    pB[4] += __shfl_xor(pB[5], 1, 64);
    pA[6] += __shfl_xor(pA[7], 1, 64);
    pB[6] += __shfl_xor(pB[7], 1, 64);
    pA[0] += __shfl_xor(pA[2], 2, 64);
    pB[0] += __shfl_xor(pB[2], 2, 64);
    pA[4] += __shfl_xor(pA[6], 2, 64);
    pB[4] += __shfl_xor(pB[6], 2, 64);
    pA[0] += __shfl_xor(pA[4], 4, 64);
    pB[0] += __shfl_xor(pB[4], 4, 64);
    pA[0] += __shfl_xor(pA[0], 8, 64);
    pB[0] += __shfl_xor(pB[0], 8, 64);
    pA[0] += __shfl_xor(pA[0], 16, 64);
    pB[0] += __shfl_xor(pB[0], 16, 64);
    pA[0] += __shfl_xor(pA[0], 32, 64);
    pB[0] += __shfl_xor(pB[0], 32, 64);
    float eA = __expf(pA[0] * 0.125f);
    float eB = __expf(pB[0] * 0.125f);
    lp += eA + eB;
    // wave-uniform head weights -> SGPRs (head h sits on lane bitrev3(h))
    float wA[8], wB[8];
#pragma unroll
    for (int h = 0; h < HH; ++h) {
      wA[h] = __uint_as_float(__builtin_amdgcn_readlane(__float_as_uint(eA), bitrev3(h)));
      wB[h] = __uint_as_float(__builtin_amdgcn_readlane(__float_as_uint(eB), bitrev3(h)));
    }
#pragma unroll
    for (int h = 0; h < HH; ++h) {
      float w1 = wA[h], w2 = wB[h];
      acc[2 * h].x = fmaf(w1, aA.x, acc[2 * h].x);
      acc[2 * h].y = fmaf(w1, aA.y, acc[2 * h].y);
      acc[2 * h].z = fmaf(w1, aA.z, acc[2 * h].z);
      acc[2 * h].w = fmaf(w1, aA.w, acc[2 * h].w);
      acc[2 * h + 1].x = fmaf(w1, dA.x, acc[2 * h + 1].x);
      acc[2 * h + 1].y = fmaf(w1, dA.y, acc[2 * h + 1].y);
      acc[2 * h + 1].z = fmaf(w1, dA.z, acc[2 * h + 1].z);
      acc[2 * h + 1].w = fmaf(w1, dA.w, acc[2 * h + 1].w);
      acc[2 * h].x = fmaf(w2, aB.x, acc[2 * h].x);
      acc[2 * h].y = fmaf(w2, aB.y, acc[2 * h].y);
      acc[2 * h].z = fmaf(w2, aB.z, acc[2 * h].z);
      acc[2 * h].w = fmaf(w2, aB.w, acc[2 * h].w);
      acc[2 * h + 1].x = fmaf(w2, dB.x, acc[2 * h + 1].x);
      acc[2 * h + 1].y = fmaf(w2, dB.y, acc[2 * h + 1].y);
      acc[2 * h + 1].z = fmaf(w2, dB.z, acc[2 * h + 1].z);
      acc[2 * h + 1].w = fmaf(w2, dB.w, acc[2 * h + 1].w);
    }
  }

  // lane L (<8) holds partial sum-of-exp for head bitrev3(L)
  if (lane < 8) lbuf[wave * 8 + bitrev3(lane)] = lp;

  for (int i = tid; i < HH * EE; i += 256) cbuf[i] = 0.f;
  __syncthreads();
  for (int w4 = 0; w4 < 4; ++w4) {
    if (wave == w4) {
#pragma unroll
      for (int h = 0; h < HH; ++h) {
        int e0 = h * EE + 4 * lane;
        cbuf[e0 + 0] += acc[2 * h].x;
        cbuf[e0 + 1] += acc[2 * h].y;
        cbuf[e0 + 2] += acc[2 * h].z;
        cbuf[e0 + 3] += acc[2 * h].w;
        int e1 = e0 + 256;
        cbuf[e1 + 0] += acc[2 * h + 1].x;
        cbuf[e1 + 1] += acc[2 * h + 1].y;
        cbuf[e1 + 2] += acc[2 * h + 1].z;
        cbuf[e1 + 3] += acc[2 * h + 1].w;
      }
    }
    __syncthreads();
  }
  float* pb = part + (size_t)b * (HH * EE);
  for (int i = tid; i < HH * EE; i += 256) pb[i] = cbuf[i];
  if (tid < 8)
    lw[b * 8 + tid] = lbuf[tid] + lbuf[8 + tid] + lbuf[16 + tid] + lbuf[24 + tid];
}

// ---- K3 (tail): combine+normalize ctx, then 3 chained GEMVs ----------------
// Block = n (32 blocks, 256 threads). 4 threads per output row; quarter
// reads rotated to avoid 4-way same-bank conflicts on the LDS source row.
__global__ __launch_bounds__(256) void k_tail(const float* __restrict__ part,
                                              const float* __restrict__ lw,
                                              const float* __restrict__ Wv,
                                              const float* __restrict__ bv,
                                              const float* __restrict__ Wo,
                                              const float* __restrict__ bo,
                                              const float* __restrict__ Wl,
                                              const float* __restrict__ bl,
                                              float* __restrict__ out) {
  __shared__ float ctxs[HH * EE];   // 16 KB (normalized ctx)
  __shared__ float buf0[EE];        // vout
  __shared__ float buf1[EE];        // y1
  __shared__ float linv[HH];
  int n = blockIdx.x, tid = threadIdx.x;
  if (tid < 128) {
    int h = tid >> 4, c = tid & 15;
    float l = lw[(n * NCHUNK + c) * 8 + h];
    l += __shfl_xor(l, 1, 64);
    l += __shfl_xor(l, 2, 64);
    l += __shfl_xor(l, 4, 64);
    l += __shfl_xor(l, 8, 64);
    if (c == 0) linv[h] = 1.f / l;
  }
  __syncthreads();
#pragma unroll
  for (int k = 0; k < 16; ++k) {
    int x = tid + k * 256;
    float s = 0.f;
#pragma unroll
    for (int c = 0; c < NCHUNK; ++c) s += part[((size_t)(n * NCHUNK + c)) * 4096 + x];
    ctxs[x] = s * linv[x >> 9];
  }
  __syncthreads();

  // phase A: buf0[r] = ctxs[h(r)*512 ..] . Wv[r,:] + bv[r]
#pragma unroll
  for (int j = 0; j < 8; ++j) {
    int slot = tid + j * 256;
    int r = slot >> 2, q = slot & 3;
    const float4* wrow = (const float4*)(Wv + (size_t)r * EE);
    const float4* cx = (const float4*)(ctxs + (r >> 6) * EE);
    float a2 = 0.f;
#pragma unroll 8
    for (int i = 0; i < 32; ++i) {
      int k = q * 32 + ((i + 2 * q) & 31);   // rotated: bank-conflict-free
      float4 a = cx[k], w = wrow[k];
      a2 = fmaf(a.x, w.x, fmaf(a.y, w.y, fmaf(a.z, w.z, fmaf(a.w, w.w, a2))));
    }
    a2 += __shfl_xor(a2, 1, 64);
    a2 += __shfl_xor(a2, 2, 64);
    if (q == 0) buf0[r] = a2 + bv[r];
  }
  __syncthreads();

  // phase B: buf1[r] = buf0 . Wo[r,:] + bo[r]
#pragma unroll
  for (int j = 0; j < 8; ++j) {
    int slot = tid + j * 256;
    int r = slot >> 2, q = slot & 3;
    const float4* wrow = (const float4*)(Wo + (size_t)r * EE);
    const float4* cx = (const float4*)buf0;
    float a2 = 0.f;
#pragma unroll 8
    for (int i = 0; i < 32; ++i) {
      int k = q * 32 + ((i + 2 * q) & 31);
      float4 a = cx[k], w = wrow[k];
      a2 = fmaf(a.x, w.x, fmaf(a.y, w.y, fmaf(a.z, w.z, fmaf(a.w, w.w, a2))));
    }
    a2 += __shfl_xor(a2, 1, 64);
    a2 += __shfl_xor(a2, 2, 64);
    if (q == 0) buf1[r] = a2 + bo[r];
  }
  __syncthreads();

  // phase C: out[n*512+r] = buf1 . Wl[r,:] + bl[r]
#pragma unroll
  for (int j = 0; j < 8; ++j) {
    int slot = tid + j * 256;
    int r = slot >> 2, q = slot & 3;
    const float4* wrow = (const float4*)(Wl + (size_t)r * EE);
    const float4* cx = (const float4*)buf1;
    float a2 = 0.f;
#pragma unroll 8
    for (int i = 0; i < 32; ++i) {
      int k = q * 32 + ((i + 2 * q) & 31);
      float4 a = cx[k], w = wrow[k];
      a2 = fmaf(a.x, w.x, fmaf(a.y, w.y, fmaf(a.z, w.z, fmaf(a.w, w.w, a2))));
    }
    a2 += __shfl_xor(a2, 1, 64);
    a2 += __shfl_xor(a2, 2, 64);
    if (q == 0) out[(size_t)n * EE + r] = a2 + bl[r];
  }
}

extern "C" void kernel_launch(void* const* d_in, const int* in_sizes, int n_in,
                              void* d_out, int out_size, void* d_ws, size_t ws_size,
                              hipStream_t stream) {
  const float* src = (const float*)d_in[0];
  const float* Wq  = (const float*)d_in[1];
  const float* bq  = (const float*)d_in[2];
  const float* Wk  = (const float*)d_in[3];
  const float* Wv  = (const float*)d_in[5];
  const float* bv  = (const float*)d_in[6];
  const float* Wo  = (const float*)d_in[7];
  const float* bo  = (const float*)d_in[8];
  const float* Wl  = (const float*)d_in[9];
  const float* bl  = (const float*)d_in[10];
  float* out = (float*)d_out;

  float* ws = (float*)d_ws;
  float* qk   = ws;                               // 131072
  float* lw   = qk + 131072;                      // 512*8 = 4096
  float* part = lw + 4096;                        // 512*4096 floats (8MB)

  k_qproj<<<256, 256, 0, stream>>>(src, Wq, bq, Wk, qk);
  k_fused<<<NB * NCHUNK, 256, 0, stream>>>(src, qk, part, lw);
  k_tail<<<NB, 256, 0, stream>>>(part, lw, Wv, bv, Wo, bo, Wl, bl, out);
}

// Round 5
// 120.173 us; speedup vs baseline: 2.1287x; 2.1287x over previous
//
#include <hip/hip_runtime.h>

// Dims (fixed): S=4096, N=32, E=512, H=8, DK=64. Query pos l = 2048 (L==1).
// qb = q.bk cancels in softmax (constant over s) -> dropped everywhere.
#define SS 4096
#define NB 32
#define EE 512
#define HH 8
#define DKK 64
#define LQ 2048
#define NCHUNK 16          // s-chunks per n in fused kernel (256 s each)

__device__ __forceinline__ constexpr int bitrev3(int x) {
  return ((x & 1) << 2) | (x & 2) | ((x & 4) >> 2);
}

// ---- K1: q[n,h,:] then qk[n,h,e] = sum_d q_d * Wk[h*64+d, e] ---------------
__global__ __launch_bounds__(256) void k_qproj(const float* __restrict__ src,
                                               const float* __restrict__ Wq,
                                               const float* __restrict__ bq,
                                               const float* __restrict__ Wk,
                                               float* __restrict__ qk) {
  __shared__ float qd[DKK];
  int n = blockIdx.x >> 3, h = blockIdx.x & 7;
  int tid = threadIdx.x;
  int d = tid >> 2, part = tid & 3;
  const float4* xs = (const float4*)(src + ((size_t)LQ * NB + n) * EE);
  const float4* wr = (const float4*)(Wq + (size_t)(h * DKK + d) * EE);
  float acc = 0.f;
#pragma unroll 8
  for (int i = 0; i < 32; ++i) {
    float4 a = xs[part * 32 + i], b = wr[part * 32 + i];
    acc = fmaf(a.x, b.x, fmaf(a.y, b.y, fmaf(a.z, b.z, fmaf(a.w, b.w, acc))));
  }
  acc += __shfl_xor(acc, 1, 64);
  acc += __shfl_xor(acc, 2, 64);
  if (part == 0) qd[d] = acc + bq[h * DKK + d];
  __syncthreads();
  float a0 = 0.f, a1 = 0.f;
#pragma unroll 8
  for (int d2 = 0; d2 < DKK; ++d2) {
    float qv = qd[d2];
    const float* row = Wk + (size_t)(h * DKK + d2) * EE;
    a0 = fmaf(qv, row[tid], a0);
    a1 = fmaf(qv, row[tid + 256], a1);
  }
  size_t base = (size_t)(n * HH + h) * EE;
  qk[base + tid] = a0;
  qk[base + tid + 256] = a1;
}

// ---- K2 (fused): one pass over src; 2 rows per wave-iter (ILP).
// Slot mapping for the dot: lane L, slot j <-> head bitrev3((L&7)^j).
// Fold reduce (10 DS) -> lane L holds full dot for head bitrev3(L&7).
// exp -> weights wave-uniform -> readlane to SGPRs. Head-major accumulate.
__global__ __launch_bounds__(256, 2) void k_fused(const float* __restrict__ src,
                                                  const float* __restrict__ qk,
                                                  float* __restrict__ part,
                                                  float* __restrict__ lw) {
  __shared__ float cbuf[HH * EE];   // 16 KB
  __shared__ float lbuf[4 * HH];
  int b = blockIdx.x;
  int n = b >> 4, c = b & 15;
  int tid = threadIdx.x, wave = tid >> 6, lane = tid & 63;

  const float4* qk4 = (const float4*)qk;
  float4 qf[16];
#pragma unroll
  for (int j = 0; j < HH; ++j) {
    int hj = bitrev3((lane ^ j) & 7);
    int qbase = (n * HH + hj) * (EE / 4);
    qf[2 * j] = qk4[qbase + lane];
    qf[2 * j + 1] = qk4[qbase + 64 + lane];
  }

  float4 acc[16];   // head-major: acc[2h], acc[2h+1]
#pragma unroll
  for (int i = 0; i < 16; ++i) acc[i] = make_float4(0.f, 0.f, 0.f, 0.f);
  float lp = 0.f;

  const size_t rowstep = (size_t)NB * (EE / 4);   // float4 step for s+1
  const float4* sp = (const float4*)src +
                     ((size_t)((c << 8) + wave * 2) * NB + n) * (EE / 4);
  float4 nA0 = sp[lane], nA1 = sp[64 + lane];
  float4 nB0 = sp[rowstep + lane], nB1 = sp[rowstep + 64 + lane];

  for (int it = 0; it < 32; ++it) {
    float4 aA = nA0, dA = nA1, aB = nB0, dB = nB1;
    if (it < 31) {
      sp += 8 * rowstep;
      nA0 = sp[lane]; nA1 = sp[64 + lane];
      nB0 = sp[rowstep + lane]; nB1 = sp[rowstep + 64 + lane];
    }
    float pA[8], pB[8];
#pragma unroll
    for (int j = 0; j < HH; ++j) {
      float4 u = qf[2 * j], v = qf[2 * j + 1];
      pA[j] = fmaf(aA.x, u.x, fmaf(aA.y, u.y, fmaf(aA.z, u.z, fmaf(aA.w, u.w,
              fmaf(dA.x, v.x, fmaf(dA.y, v.y, fmaf(dA.z, v.z, dA.w * v.w)))))));
      pB[j] = fmaf(aB.x, u.x, fmaf(aB.y, u.y, fmaf(aB.z, u.z, fmaf(aB.w, u.w,
              fmaf(dB.x, v.x, fmaf(dB.y, v.y, fmaf(dB.z, v.z, dB.w * v.w)))))));
    }
    pA[0] += __shfl_xor(pA[1], 1, 64);
    pB[0] += __shfl_xor(pB[1], 1, 64);
    pA[2] += __shfl_xor(pA[3], 1, 64);
    pB[2] += __shfl_xor(pB[3], 1, 64);
    pA[4] += __shfl_xor(pA[5], 1, 64);
    pB[4] += __shfl_xor(pB[5], 1, 64);
    pA[6] += __shfl_xor(pA[7], 1, 64);
    pB[6] += __shfl_xor(pB[7], 1, 64);
    pA[0] += __shfl_xor(pA[2], 2, 64);
    pB[0] += __shfl_xor(pB[2], 2, 64);
    pA[4] += __shfl_xor(pA[6], 2, 64);
    pB[4] += __shfl_xor(pB[6], 2, 64);
    pA[0] += __shfl_xor(pA[4], 4, 64);
    pB[0] += __shfl_xor(pB[4], 4, 64);
    pA[0] += __shfl_xor(pA[0], 8, 64);
    pB[0] += __shfl_xor(pB[0], 8, 64);
    pA[0] += __shfl_xor(pA[0], 16, 64);
    pB[0] += __shfl_xor(pB[0], 16, 64);
    pA[0] += __shfl_xor(pA[0], 32, 64);
    pB[0] += __shfl_xor(pB[0], 32, 64);
    float eA = __expf(pA[0] * 0.125f);
    float eB = __expf(pB[0] * 0.125f);
    lp += eA + eB;
    float wA[8], wB[8];
#pragma unroll
    for (int h = 0; h < HH; ++h) {
      wA[h] = __uint_as_float(__builtin_amdgcn_readlane(__float_as_uint(eA), bitrev3(h)));
      wB[h] = __uint_as_float(__builtin_amdgcn_readlane(__float_as_uint(eB), bitrev3(h)));
    }
#pragma unroll
    for (int h = 0; h < HH; ++h) {
      float w1 = wA[h], w2 = wB[h];
      acc[2 * h].x = fmaf(w1, aA.x, acc[2 * h].x);
      acc[2 * h].y = fmaf(w1, aA.y, acc[2 * h].y);
      acc[2 * h].z = fmaf(w1, aA.z, acc[2 * h].z);
      acc[2 * h].w = fmaf(w1, aA.w, acc[2 * h].w);
      acc[2 * h + 1].x = fmaf(w1, dA.x, acc[2 * h + 1].x);
      acc[2 * h + 1].y = fmaf(w1, dA.y, acc[2 * h + 1].y);
      acc[2 * h + 1].z = fmaf(w1, dA.z, acc[2 * h + 1].z);
      acc[2 * h + 1].w = fmaf(w1, dA.w, acc[2 * h + 1].w);
      acc[2 * h].x = fmaf(w2, aB.x, acc[2 * h].x);
      acc[2 * h].y = fmaf(w2, aB.y, acc[2 * h].y);
      acc[2 * h].z = fmaf(w2, aB.z, acc[2 * h].z);
      acc[2 * h].w = fmaf(w2, aB.w, acc[2 * h].w);
      acc[2 * h + 1].x = fmaf(w2, dB.x, acc[2 * h + 1].x);
      acc[2 * h + 1].y = fmaf(w2, dB.y, acc[2 * h + 1].y);
      acc[2 * h + 1].z = fmaf(w2, dB.z, acc[2 * h + 1].z);
      acc[2 * h + 1].w = fmaf(w2, dB.w, acc[2 * h + 1].w);
    }
  }

  if (lane < 8) lbuf[wave * 8 + bitrev3(lane)] = lp;

  for (int i = tid; i < HH * EE; i += 256) cbuf[i] = 0.f;
  __syncthreads();
  for (int w4 = 0; w4 < 4; ++w4) {
    if (wave == w4) {
#pragma unroll
      for (int h = 0; h < HH; ++h) {
        int e0 = h * EE + 4 * lane;
        cbuf[e0 + 0] += acc[2 * h].x;
        cbuf[e0 + 1] += acc[2 * h].y;
        cbuf[e0 + 2] += acc[2 * h].z;
        cbuf[e0 + 3] += acc[2 * h].w;
        int e1 = e0 + 256;
        cbuf[e1 + 0] += acc[2 * h + 1].x;
        cbuf[e1 + 1] += acc[2 * h + 1].y;
        cbuf[e1 + 2] += acc[2 * h + 1].z;
        cbuf[e1 + 3] += acc[2 * h + 1].w;
      }
    }
    __syncthreads();
  }
  float* pb = part + (size_t)b * (HH * EE);
  for (int i = tid; i < HH * EE; i += 256) pb[i] = cbuf[i];
  if (tid < 8)
    lw[b * 8 + tid] = lbuf[tid] + lbuf[8 + tid] + lbuf[16 + tid] + lbuf[24 + tid];
}

// ---- K3: combine partials + normalize + Wv projection (block = (n,h)) ------
__global__ __launch_bounds__(256) void k_voutc(const float* __restrict__ part,
                                               const float* __restrict__ lw,
                                               const float* __restrict__ Wv,
                                               const float* __restrict__ bv,
                                               float* __restrict__ vout) {
  __shared__ float ctxs[EE];
  __shared__ float linv_s;
  int n = blockIdx.x >> 3, h = blockIdx.x & 7;
  int tid = threadIdx.x;
  if (tid < 16) {
    float l = lw[(n * NCHUNK + tid) * 8 + h];
    l += __shfl_xor(l, 1, 64);
    l += __shfl_xor(l, 2, 64);
    l += __shfl_xor(l, 4, 64);
    l += __shfl_xor(l, 8, 64);
    if (tid == 0) linv_s = 1.f / l;
  }
  float s0 = 0.f, s1 = 0.f;
#pragma unroll
  for (int c = 0; c < NCHUNK; ++c) {
    const float* pb = part + ((size_t)(n * NCHUNK + c) * 4096) + h * EE;
    s0 += pb[tid];
    s1 += pb[tid + 256];
  }
  ctxs[tid] = s0;
  ctxs[tid + 256] = s1;
  __syncthreads();
  // vout[r] for r = h*64 + rr; 4 threads per r over rotated 128-elem quarters
  int rr = tid >> 2, q = tid & 3;
  int r = h * 64 + rr;
  const float4* wrow = (const float4*)(Wv + (size_t)r * EE);
  const float4* cx = (const float4*)ctxs;
  float acc = 0.f;
#pragma unroll 8
  for (int i = 0; i < 32; ++i) {
    int k = q * 32 + ((i + 2 * q) & 31);
    float4 a = cx[k], b2 = wrow[k];
    acc = fmaf(a.x, b2.x, fmaf(a.y, b2.y, fmaf(a.z, b2.z, fmaf(a.w, b2.w, acc))));
  }
  acc += __shfl_xor(acc, 1, 64);
  acc += __shfl_xor(acc, 2, 64);
  if (q == 0) vout[n * EE + r] = acc * linv_s + bv[r];
}

// ---- K4/K5: y[n,r] = x[n,:].W[r,:] + b[r] ----------------------------------
__global__ __launch_bounds__(256) void k_lin(const float* __restrict__ x,
                                             const float* __restrict__ W,
                                             const float* __restrict__ bias,
                                             float* __restrict__ y) {
  int t = blockIdx.x * 256 + threadIdx.x;  // 16384
  int r = t >> 5, n = t & 31;
  const float4* x4 = (const float4*)(x + (size_t)n * EE);
  const float4* w4 = (const float4*)(W + (size_t)r * EE);
  float acc = 0.f;
#pragma unroll 8
  for (int i = 0; i < EE / 4; ++i) {
    float4 a = x4[i], b = w4[i];
    acc = fmaf(a.x, b.x, fmaf(a.y, b.y, fmaf(a.z, b.z, fmaf(a.w, b.w, acc))));
  }
  y[n * EE + r] = acc + bias[r];
}

extern "C" void kernel_launch(void* const* d_in, const int* in_sizes, int n_in,
                              void* d_out, int out_size, void* d_ws, size_t ws_size,
                              hipStream_t stream) {
  const float* src = (const float*)d_in[0];
  const float* Wq  = (const float*)d_in[1];
  const float* bq  = (const float*)d_in[2];
  const float* Wk  = (const float*)d_in[3];
  const float* Wv  = (const float*)d_in[5];
  const float* bv  = (const float*)d_in[6];
  const float* Wo  = (const float*)d_in[7];
  const float* bo  = (const float*)d_in[8];
  const float* Wl  = (const float*)d_in[9];
  const float* bl  = (const float*)d_in[10];
  float* out = (float*)d_out;

  float* ws = (float*)d_ws;
  float* qk   = ws;                               // 131072
  float* lw   = qk + 131072;                      // 512*8 = 4096
  float* vout = lw + 4096;                        // 16384
  float* y1   = vout + 16384;                     // 16384
  float* part = y1 + 16384;                       // 512*4096 floats (8MB)

  k_qproj<<<256, 256, 0, stream>>>(src, Wq, bq, Wk, qk);
  k_fused<<<NB * NCHUNK, 256, 0, stream>>>(src, qk, part, lw);
  k_voutc<<<256, 256, 0, stream>>>(part, lw, Wv, bv, vout);
  k_lin<<<64, 256, 0, stream>>>(vout, Wo, bo, y1);
  k_lin<<<64, 256, 0, stream>>>(y1, Wl, bl, out);
}

// Round 6
// 118.413 us; speedup vs baseline: 2.1603x; 1.0149x over previous
//
#include <hip/hip_runtime.h>

// Dims (fixed): S=4096, N=32, E=512, H=8, DK=64. Query pos l = 2048 (L==1).
// qb = q.bk cancels in softmax (constant over s) -> dropped everywhere.
#define SS 4096
#define NB 32
#define EE 512
#define HH 8
#define DKK 64
#define LQ 2048
#define NCHUNK 16          // s-chunks per n in fused kernel (256 s each)

// DPP cross-lane add: dst += perm(src), perm within 16-lane rows (VALU pipe,
// no DS). Controls: quad_perm(1,0,3,2)=0xB1 -> xor1; quad_perm(2,3,0,1)=0x4E
// -> xor2; ROW_HALF_MIRROR=0x141 -> xor7 (within 8); ROW_ROR:8=0x128 -> xor8
// (within 16). All lanes active at every use site.
#define DPPADD(dst, src, ctrl)                                              \
  dst += __int_as_float(__builtin_amdgcn_update_dpp(                        \
      0, __float_as_int(src), ctrl, 0xF, 0xF, true))

// ---- K1: q[n,h,:] then qk[n,h,e] = sum_d q_d * Wk[h*64+d, e] ---------------
__global__ __launch_bounds__(256) void k_qproj(const float* __restrict__ src,
                                               const float* __restrict__ Wq,
                                               const float* __restrict__ bq,
                                               const float* __restrict__ Wk,
                                               float* __restrict__ qk) {
  __shared__ float qd[DKK];
  int n = blockIdx.x >> 3, h = blockIdx.x & 7;
  int tid = threadIdx.x;
  int d = tid >> 2, part = tid & 3;
  const float4* xs = (const float4*)(src + ((size_t)LQ * NB + n) * EE);
  const float4* wr = (const float4*)(Wq + (size_t)(h * DKK + d) * EE);
  float acc = 0.f;
#pragma unroll 8
  for (int i = 0; i < 32; ++i) {
    float4 a = xs[part * 32 + i], b = wr[part * 32 + i];
    acc = fmaf(a.x, b.x, fmaf(a.y, b.y, fmaf(a.z, b.z, fmaf(a.w, b.w, acc))));
  }
  DPPADD(acc, acc, 0xB1);   // xor1
  DPPADD(acc, acc, 0x4E);   // xor2
  if (part == 0) qd[d] = acc + bq[h * DKK + d];
  __syncthreads();
  float a0 = 0.f, a1 = 0.f;
#pragma unroll 8
  for (int d2 = 0; d2 < DKK; ++d2) {
    float qv = qd[d2];
    const float* row = Wk + (size_t)(h * DKK + d2) * EE;
    a0 = fmaf(qv, row[tid], a0);
    a1 = fmaf(qv, row[tid + 256], a1);
  }
  size_t base = (size_t)(n * HH + h) * EE;
  qk[base + tid] = a0;
  qk[base + tid + 256] = a1;
}

// ---- K2 (fused): one pass over src; 2 rows/wave-iter.
// Slot offsets s = {0,1,2,3,7,6,5,4}: slot j of lane L holds head (L&7)^s_j.
// Fold stages use masks {1,2,7,8} as DPP (VALU) + {16,32} as shuffles (DS).
// Invariant checked per stage: s_src = s_dst ^ mask. Final: lane L holds the
// full 64-lane dot for head L&7. exp -> weights wave-uniform -> readlane.
__global__ __launch_bounds__(256, 2) void k_fused(const float* __restrict__ src,
                                                  const float* __restrict__ qk,
                                                  float* __restrict__ part,
                                                  float* __restrict__ lw) {
  __shared__ float cbuf[HH * EE];   // 16 KB
  __shared__ float lbuf[4 * HH];
  int b = blockIdx.x;
  int n = b >> 4, c = b & 15;
  int tid = threadIdx.x, wave = tid >> 6, lane = tid & 63;

  const int SLOT[8] = {0, 1, 2, 3, 7, 6, 5, 4};
  const float4* qk4 = (const float4*)qk;
  float4 qf[16];
#pragma unroll
  for (int j = 0; j < HH; ++j) {
    int hj = (lane & 7) ^ SLOT[j];
    int qbase = (n * HH + hj) * (EE / 4);
    qf[2 * j] = qk4[qbase + lane];
    qf[2 * j + 1] = qk4[qbase + 64 + lane];
  }

  float4 acc[16];   // head-major: acc[2h], acc[2h+1]
#pragma unroll
  for (int i = 0; i < 16; ++i) acc[i] = make_float4(0.f, 0.f, 0.f, 0.f);
  float lp = 0.f;

  const size_t rowstep = (size_t)NB * (EE / 4);   // float4 step for s+1
  const float4* sp = (const float4*)src +
                     ((size_t)((c << 8) + wave * 2) * NB + n) * (EE / 4);
  float4 nA0 = sp[lane], nA1 = sp[64 + lane];
  float4 nB0 = sp[rowstep + lane], nB1 = sp[rowstep + 64 + lane];

  for (int it = 0; it < 32; ++it) {
    float4 aA = nA0, dA = nA1, aB = nB0, dB = nB1;
    if (it < 31) {
      sp += 8 * rowstep;
      nA0 = sp[lane]; nA1 = sp[64 + lane];
      nB0 = sp[rowstep + lane]; nB1 = sp[rowstep + 64 + lane];
    }
    float pA[8], pB[8];
#pragma unroll
    for (int j = 0; j < HH; ++j) {
      float4 u = qf[2 * j], v = qf[2 * j + 1];
      pA[j] = fmaf(aA.x, u.x, fmaf(aA.y, u.y, fmaf(aA.z, u.z, fmaf(aA.w, u.w,
              fmaf(dA.x, v.x, fmaf(dA.y, v.y, fmaf(dA.z, v.z, dA.w * v.w)))))));
      pB[j] = fmaf(aB.x, u.x, fmaf(aB.y, u.y, fmaf(aB.z, u.z, fmaf(aB.w, u.w,
              fmaf(dB.x, v.x, fmaf(dB.y, v.y, fmaf(dB.z, v.z, dB.w * v.w)))))));
    }
    // fold reduce, DPP stages (VALU): masks 1,1,1,1 / 2,2 / 7 / 8
    DPPADD(pA[0], pA[1], 0xB1);  DPPADD(pB[0], pB[1], 0xB1);
    DPPADD(pA[2], pA[3], 0xB1);  DPPADD(pB[2], pB[3], 0xB1);
    DPPADD(pA[4], pA[5], 0xB1);  DPPADD(pB[4], pB[5], 0xB1);
    DPPADD(pA[6], pA[7], 0xB1);  DPPADD(pB[6], pB[7], 0xB1);
    DPPADD(pA[0], pA[2], 0x4E);  DPPADD(pB[0], pB[2], 0x4E);
    DPPADD(pA[4], pA[6], 0x4E);  DPPADD(pB[4], pB[6], 0x4E);
    DPPADD(pA[0], pA[4], 0x141); DPPADD(pB[0], pB[4], 0x141);
    DPPADD(pA[0], pA[0], 0x128); DPPADD(pB[0], pB[0], 0x128);
    // cross-row stages (DS): xor16, xor32
    pA[0] += __shfl_xor(pA[0], 16, 64);
    pB[0] += __shfl_xor(pB[0], 16, 64);
    pA[0] += __shfl_xor(pA[0], 32, 64);
    pB[0] += __shfl_xor(pB[0], 32, 64);
    float eA = __expf(pA[0] * 0.125f);
    float eB = __expf(pB[0] * 0.125f);
    lp += eA + eB;
    // head h's weight sits on lane h (and duplicates) -> readlane to SGPR
    float wA[8], wB[8];
#pragma unroll
    for (int h = 0; h < HH; ++h) {
      wA[h] = __uint_as_float(__builtin_amdgcn_readlane(__float_as_uint(eA), h));
      wB[h] = __uint_as_float(__builtin_amdgcn_readlane(__float_as_uint(eB), h));
    }
#pragma unroll
    for (int h = 0; h < HH; ++h) {
      float w1 = wA[h], w2 = wB[h];
      acc[2 * h].x = fmaf(w1, aA.x, acc[2 * h].x);
      acc[2 * h].y = fmaf(w1, aA.y, acc[2 * h].y);
      acc[2 * h].z = fmaf(w1, aA.z, acc[2 * h].z);
      acc[2 * h].w = fmaf(w1, aA.w, acc[2 * h].w);
      acc[2 * h + 1].x = fmaf(w1, dA.x, acc[2 * h + 1].x);
      acc[2 * h + 1].y = fmaf(w1, dA.y, acc[2 * h + 1].y);
      acc[2 * h + 1].z = fmaf(w1, dA.z, acc[2 * h + 1].z);
      acc[2 * h + 1].w = fmaf(w1, dA.w, acc[2 * h + 1].w);
      acc[2 * h].x = fmaf(w2, aB.x, acc[2 * h].x);
      acc[2 * h].y = fmaf(w2, aB.y, acc[2 * h].y);
      acc[2 * h].z = fmaf(w2, aB.z, acc[2 * h].z);
      acc[2 * h].w = fmaf(w2, aB.w, acc[2 * h].w);
      acc[2 * h + 1].x = fmaf(w2, dB.x, acc[2 * h + 1].x);
      acc[2 * h + 1].y = fmaf(w2, dB.y, acc[2 * h + 1].y);
      acc[2 * h + 1].z = fmaf(w2, dB.z, acc[2 * h + 1].z);
      acc[2 * h + 1].w = fmaf(w2, dB.w, acc[2 * h + 1].w);
    }
  }

  // lane L (<8) holds partial sum-of-exp for head L
  if (lane < 8) lbuf[wave * 8 + lane] = lp;

  for (int i = tid; i < HH * EE; i += 256) cbuf[i] = 0.f;
  __syncthreads();
  for (int w4 = 0; w4 < 4; ++w4) {
    if (wave == w4) {
#pragma unroll
      for (int h = 0; h < HH; ++h) {
        int e0 = h * EE + 4 * lane;
        cbuf[e0 + 0] += acc[2 * h].x;
        cbuf[e0 + 1] += acc[2 * h].y;
        cbuf[e0 + 2] += acc[2 * h].z;
        cbuf[e0 + 3] += acc[2 * h].w;
        int e1 = e0 + 256;
        cbuf[e1 + 0] += acc[2 * h + 1].x;
        cbuf[e1 + 1] += acc[2 * h + 1].y;
        cbuf[e1 + 2] += acc[2 * h + 1].z;
        cbuf[e1 + 3] += acc[2 * h + 1].w;
      }
    }
    __syncthreads();
  }
  float* pb = part + (size_t)b * (HH * EE);
  for (int i = tid; i < HH * EE; i += 256) pb[i] = cbuf[i];
  if (tid < 8)
    lw[b * 8 + tid] = lbuf[tid] + lbuf[8 + tid] + lbuf[16 + tid] + lbuf[24 + tid];
}

// ---- K3: combine partials + normalize + Wv projection (block = (n,h)) ------
__global__ __launch_bounds__(256) void k_voutc(const float* __restrict__ part,
                                               const float* __restrict__ lw,
                                               const float* __restrict__ Wv,
                                               const float* __restrict__ bv,
                                               float* __restrict__ vout) {
  __shared__ float ctxs[EE];
  __shared__ float linv_s;
  int n = blockIdx.x >> 3, h = blockIdx.x & 7;
  int tid = threadIdx.x;
  if (tid < 16) {
    float l = lw[(n * NCHUNK + tid) * 8 + h];
    DPPADD(l, l, 0xB1);    // xor1
    DPPADD(l, l, 0x4E);    // xor2
    DPPADD(l, l, 0x141);   // xor7 (completes 8-group with 1,2)
    DPPADD(l, l, 0x128);   // xor8
    if (tid == 0) linv_s = 1.f / l;
  }
  float s0 = 0.f, s1 = 0.f;
#pragma unroll
  for (int c = 0; c < NCHUNK; ++c) {
    const float* pb = part + ((size_t)(n * NCHUNK + c) * 4096) + h * EE;
    s0 += pb[tid];
    s1 += pb[tid + 256];
  }
  ctxs[tid] = s0;
  ctxs[tid + 256] = s1;
  __syncthreads();
  // vout[r] for r = h*64 + rr; 4 threads per r over rotated 128-elem quarters
  int rr = tid >> 2, q = tid & 3;
  int r = h * 64 + rr;
  const float4* wrow = (const float4*)(Wv + (size_t)r * EE);
  const float4* cx = (const float4*)ctxs;
  float acc = 0.f;
#pragma unroll 8
  for (int i = 0; i < 32; ++i) {
    int k = q * 32 + ((i + 2 * q) & 31);
    float4 a = cx[k], b2 = wrow[k];
    acc = fmaf(a.x, b2.x, fmaf(a.y, b2.y, fmaf(a.z, b2.z, fmaf(a.w, b2.w, acc))));
  }
  DPPADD(acc, acc, 0xB1);
  DPPADD(acc, acc, 0x4E);
  if (q == 0) vout[n * EE + r] = acc * linv_s + bv[r];
}

// ---- K4/K5: y[n,r] = x[n,:].W[r,:] + b[r] ----------------------------------
__global__ __launch_bounds__(256) void k_lin(const float* __restrict__ x,
                                             const float* __restrict__ W,
                                             const float* __restrict__ bias,
                                             float* __restrict__ y) {
  int t = blockIdx.x * 256 + threadIdx.x;  // 16384
  int r = t >> 5, n = t & 31;
  const float4* x4 = (const float4*)(x + (size_t)n * EE);
  const float4* w4 = (const float4*)(W + (size_t)r * EE);
  float acc = 0.f;
#pragma unroll 8
  for (int i = 0; i < EE / 4; ++i) {
    float4 a = x4[i], b = w4[i];
    acc = fmaf(a.x, b.x, fmaf(a.y, b.y, fmaf(a.z, b.z, fmaf(a.w, b.w, acc))));
  }
  y[n * EE + r] = acc + bias[r];
}

extern "C" void kernel_launch(void* const* d_in, const int* in_sizes, int n_in,
                              void* d_out, int out_size, void* d_ws, size_t ws_size,
                              hipStream_t stream) {
  const float* src = (const float*)d_in[0];
  const float* Wq  = (const float*)d_in[1];
  const float* bq  = (const float*)d_in[2];
  const float* Wk  = (const float*)d_in[3];
  const float* Wv  = (const float*)d_in[5];
  const float* bv  = (const float*)d_in[6];
  const float* Wo  = (const float*)d_in[7];
  const float* bo  = (const float*)d_in[8];
  const float* Wl  = (const float*)d_in[9];
  const float* bl  = (const float*)d_in[10];
  float* out = (float*)d_out;

  float* ws = (float*)d_ws;
  float* qk   = ws;                               // 131072
  float* lw   = qk + 131072;                      // 512*8 = 4096
  float* vout = lw + 4096;                        // 16384
  float* y1   = vout + 16384;                     // 16384
  float* part = y1 + 16384;                       // 512*4096 floats (8MB)

  k_qproj<<<256, 256, 0, stream>>>(src, Wq, bq, Wk, qk);
  k_fused<<<NB * NCHUNK, 256, 0, stream>>>(src, qk, part, lw);
  k_voutc<<<256, 256, 0, stream>>>(part, lw, Wv, bv, vout);
  k_lin<<<64, 256, 0, stream>>>(vout, Wo, bo, y1);
  k_lin<<<64, 256, 0, stream>>>(y1, Wl, bl, out);
}

// Round 7
// 81.903 us; speedup vs baseline: 3.1233x; 1.4458x over previous
//
#include <hip/hip_runtime.h>

// Dims (fixed): S=4096, N=32, E=512, H=8, DK=64. Query pos l = 2048 (L==1).
// qb = q.bk cancels in softmax (constant over s) -> dropped everywhere.
#define SS 4096
#define NB 32
#define EE 512
#define HH 8
#define DKK 64
#define LQ 2048
#define NCHUNK 16          // s-chunks per n in fused kernel (256 s each)

// DPP cross-lane add: dst += perm(src) on the VALU pipe (no DS).
// 0xB1 quad_perm(1,0,3,2)=xor1; 0x4E quad_perm(2,3,0,1)=xor2;
// 0x141 ROW_HALF_MIRROR=xor7 (within 8); 0x128 ROW_ROR:8=xor8 (within 16).
#define DPPADD(dst, src, ctrl)                                              \
  dst += __int_as_float(__builtin_amdgcn_update_dpp(                        \
      0, __float_as_int(src), ctrl, 0xF, 0xF, true))

// ---- K1: q[n,h,:] then qk[n,h,e] = sum_d q_d * Wk[h*64+d, e] ---------------
__global__ __launch_bounds__(256) void k_qproj(const float* __restrict__ src,
                                               const float* __restrict__ Wq,
                                               const float* __restrict__ bq,
                                               const float* __restrict__ Wk,
                                               float* __restrict__ qk) {
  __shared__ float qd[DKK];
  int n = blockIdx.x >> 3, h = blockIdx.x & 7;
  int tid = threadIdx.x;
  int d = tid >> 2, part = tid & 3;
  const float4* xs = (const float4*)(src + ((size_t)LQ * NB + n) * EE);
  const float4* wr = (const float4*)(Wq + (size_t)(h * DKK + d) * EE);
  float acc = 0.f;
#pragma unroll 8
  for (int i = 0; i < 32; ++i) {
    float4 a = xs[part * 32 + i], b = wr[part * 32 + i];
    acc = fmaf(a.x, b.x, fmaf(a.y, b.y, fmaf(a.z, b.z, fmaf(a.w, b.w, acc))));
  }
  DPPADD(acc, acc, 0xB1);   // xor1
  DPPADD(acc, acc, 0x4E);   // xor2
  if (part == 0) qd[d] = acc + bq[h * DKK + d];
  __syncthreads();
  float a0 = 0.f, a1 = 0.f;
#pragma unroll 8
  for (int d2 = 0; d2 < DKK; ++d2) {
    float qv = qd[d2];
    const float* row = Wk + (size_t)(h * DKK + d2) * EE;
    a0 = fmaf(qv, row[tid], a0);
    a1 = fmaf(qv, row[tid + 256], a1);
  }
  size_t base = (size_t)(n * HH + h) * EE;
  qk[base + tid] = a0;
  qk[base + tid + 256] = a1;
}

// ---- K2 (fused): one pass over src; 2 rows/wave-iter. (unchanged, validated)
__global__ __launch_bounds__(256, 2) void k_fused(const float* __restrict__ src,
                                                  const float* __restrict__ qk,
                                                  float* __restrict__ part,
                                                  float* __restrict__ lw) {
  __shared__ float cbuf[HH * EE];   // 16 KB
  __shared__ float lbuf[4 * HH];
  int b = blockIdx.x;
  int n = b >> 4, c = b & 15;
  int tid = threadIdx.x, wave = tid >> 6, lane = tid & 63;

  const int SLOT[8] = {0, 1, 2, 3, 7, 6, 5, 4};
  const float4* qk4 = (const float4*)qk;
  float4 qf[16];
#pragma unroll
  for (int j = 0; j < HH; ++j) {
    int hj = (lane & 7) ^ SLOT[j];
    int qbase = (n * HH + hj) * (EE / 4);
    qf[2 * j] = qk4[qbase + lane];
    qf[2 * j + 1] = qk4[qbase + 64 + lane];
  }

  float4 acc[16];   // head-major: acc[2h], acc[2h+1]
#pragma unroll
  for (int i = 0; i < 16; ++i) acc[i] = make_float4(0.f, 0.f, 0.f, 0.f);
  float lp = 0.f;

  const size_t rowstep = (size_t)NB * (EE / 4);   // float4 step for s+1
  const float4* sp = (const float4*)src +
                     ((size_t)((c << 8) + wave * 2) * NB + n) * (EE / 4);
  float4 nA0 = sp[lane], nA1 = sp[64 + lane];
  float4 nB0 = sp[rowstep + lane], nB1 = sp[rowstep + 64 + lane];

  for (int it = 0; it < 32; ++it) {
    float4 aA = nA0, dA = nA1, aB = nB0, dB = nB1;
    if (it < 31) {
      sp += 8 * rowstep;
      nA0 = sp[lane]; nA1 = sp[64 + lane];
      nB0 = sp[rowstep + lane]; nB1 = sp[rowstep + 64 + lane];
    }
    float pA[8], pB[8];
#pragma unroll
    for (int j = 0; j < HH; ++j) {
      float4 u = qf[2 * j], v = qf[2 * j + 1];
      pA[j] = fmaf(aA.x, u.x, fmaf(aA.y, u.y, fmaf(aA.z, u.z, fmaf(aA.w, u.w,
              fmaf(dA.x, v.x, fmaf(dA.y, v.y, fmaf(dA.z, v.z, dA.w * v.w)))))));
      pB[j] = fmaf(aB.x, u.x, fmaf(aB.y, u.y, fmaf(aB.z, u.z, fmaf(aB.w, u.w,
              fmaf(dB.x, v.x, fmaf(dB.y, v.y, fmaf(dB.z, v.z, dB.w * v.w)))))));
    }
    DPPADD(pA[0], pA[1], 0xB1);  DPPADD(pB[0], pB[1], 0xB1);
    DPPADD(pA[2], pA[3], 0xB1);  DPPADD(pB[2], pB[3], 0xB1);
    DPPADD(pA[4], pA[5], 0xB1);  DPPADD(pB[4], pB[5], 0xB1);
    DPPADD(pA[6], pA[7], 0xB1);  DPPADD(pB[6], pB[7], 0xB1);
    DPPADD(pA[0], pA[2], 0x4E);  DPPADD(pB[0], pB[2], 0x4E);
    DPPADD(pA[4], pA[6], 0x4E);  DPPADD(pB[4], pB[6], 0x4E);
    DPPADD(pA[0], pA[4], 0x141); DPPADD(pB[0], pB[4], 0x141);
    DPPADD(pA[0], pA[0], 0x128); DPPADD(pB[0], pB[0], 0x128);
    pA[0] += __shfl_xor(pA[0], 16, 64);
    pB[0] += __shfl_xor(pB[0], 16, 64);
    pA[0] += __shfl_xor(pA[0], 32, 64);
    pB[0] += __shfl_xor(pB[0], 32, 64);
    float eA = __expf(pA[0] * 0.125f);
    float eB = __expf(pB[0] * 0.125f);
    lp += eA + eB;
    float wA[8], wB[8];
#pragma unroll
    for (int h = 0; h < HH; ++h) {
      wA[h] = __uint_as_float(__builtin_amdgcn_readlane(__float_as_uint(eA), h));
      wB[h] = __uint_as_float(__builtin_amdgcn_readlane(__float_as_uint(eB), h));
    }
#pragma unroll
    for (int h = 0; h < HH; ++h) {
      float w1 = wA[h], w2 = wB[h];
      acc[2 * h].x = fmaf(w1, aA.x, acc[2 * h].x);
      acc[2 * h].y = fmaf(w1, aA.y, acc[2 * h].y);
      acc[2 * h].z = fmaf(w1, aA.z, acc[2 * h].z);
      acc[2 * h].w = fmaf(w1, aA.w, acc[2 * h].w);
      acc[2 * h + 1].x = fmaf(w1, dA.x, acc[2 * h + 1].x);
      acc[2 * h + 1].y = fmaf(w1, dA.y, acc[2 * h + 1].y);
      acc[2 * h + 1].z = fmaf(w1, dA.z, acc[2 * h + 1].z);
      acc[2 * h + 1].w = fmaf(w1, dA.w, acc[2 * h + 1].w);
      acc[2 * h].x = fmaf(w2, aB.x, acc[2 * h].x);
      acc[2 * h].y = fmaf(w2, aB.y, acc[2 * h].y);
      acc[2 * h].z = fmaf(w2, aB.z, acc[2 * h].z);
      acc[2 * h].w = fmaf(w2, aB.w, acc[2 * h].w);
      acc[2 * h + 1].x = fmaf(w2, dB.x, acc[2 * h + 1].x);
      acc[2 * h + 1].y = fmaf(w2, dB.y, acc[2 * h + 1].y);
      acc[2 * h + 1].z = fmaf(w2, dB.z, acc[2 * h + 1].z);
      acc[2 * h + 1].w = fmaf(w2, dB.w, acc[2 * h + 1].w);
    }
  }

  if (lane < 8) lbuf[wave * 8 + lane] = lp;

  for (int i = tid; i < HH * EE; i += 256) cbuf[i] = 0.f;
  __syncthreads();
  for (int w4 = 0; w4 < 4; ++w4) {
    if (wave == w4) {
#pragma unroll
      for (int h = 0; h < HH; ++h) {
        int e0 = h * EE + 4 * lane;
        cbuf[e0 + 0] += acc[2 * h].x;
        cbuf[e0 + 1] += acc[2 * h].y;
        cbuf[e0 + 2] += acc[2 * h].z;
        cbuf[e0 + 3] += acc[2 * h].w;
        int e1 = e0 + 256;
        cbuf[e1 + 0] += acc[2 * h + 1].x;
        cbuf[e1 + 1] += acc[2 * h + 1].y;
        cbuf[e1 + 2] += acc[2 * h + 1].z;
        cbuf[e1 + 3] += acc[2 * h + 1].w;
      }
    }
    __syncthreads();
  }
  float* pb = part + (size_t)b * (HH * EE);
  for (int i = tid; i < HH * EE; i += 256) pb[i] = cbuf[i];
  if (tid < 8)
    lw[b * 8 + tid] = lbuf[tid] + lbuf[8 + tid] + lbuf[16 + tid] + lbuf[24 + tid];
}

// ---- K3: ctx[n*8+h][e] = (sum_c part) / (sum_c lw)  ------------------------
__global__ __launch_bounds__(256) void k_combine(const float* __restrict__ part,
                                                 const float* __restrict__ lw,
                                                 float* __restrict__ ctx) {
  int t = blockIdx.x * 256 + threadIdx.x;  // 131072
  int n = t >> 12, x = t & 4095, h = x >> 9;
  float s = 0.f, lt = 0.f;
#pragma unroll
  for (int c = 0; c < NCHUNK; ++c) {
    s += part[(size_t)(n * NCHUNK + c) * 4096 + x];
    lt += lw[(n * NCHUNK + c) * 8 + h];
  }
  ctx[t] = s / lt;
}

// ---- K4-K6: wide GEMV. y[n,r] = x[row(n,r), :] . W[r,:] + b[r].
// Grid 2048 = (r, n-octet g); 1 wave. W row coalesced (64 lanes x float4 x 2).
// 8 outputs per wave via DPP slot-fold (masks 1,2,7 + xor8/16/32).
// HMAP=1: x rows are ctx[n*8+h] with h = r>>6 (Wv stage); else x rows = n.
template <int HMAP>
__global__ __launch_bounds__(64) void k_gemv(const float* __restrict__ x,
                                             const float* __restrict__ W,
                                             const float* __restrict__ bias,
                                             float* __restrict__ y) {
  int r = blockIdx.x >> 2, g = blockIdx.x & 3;
  int lane = threadIdx.x;
  const float4* W4 = (const float4*)W;
  const float4* x4 = (const float4*)x;
  float4 w0 = W4[r * 128 + lane];
  float4 w1 = W4[r * 128 + 64 + lane];
  const int SLOT[8] = {0, 1, 2, 3, 7, 6, 5, 4};
  float acc[8];
#pragma unroll
  for (int j = 0; j < 8; ++j) {
    int n = g * 8 + ((lane & 7) ^ SLOT[j]);
    int row = HMAP ? (n * 8 + (r >> 6)) : n;
    float4 a = x4[row * 128 + lane], d = x4[row * 128 + 64 + lane];
    acc[j] = fmaf(a.x, w0.x, fmaf(a.y, w0.y, fmaf(a.z, w0.z, fmaf(a.w, w0.w,
             fmaf(d.x, w1.x, fmaf(d.y, w1.y, fmaf(d.z, w1.z, d.w * w1.w)))))));
  }
  DPPADD(acc[0], acc[1], 0xB1);
  DPPADD(acc[2], acc[3], 0xB1);
  DPPADD(acc[4], acc[5], 0xB1);
  DPPADD(acc[6], acc[7], 0xB1);
  DPPADD(acc[0], acc[2], 0x4E);
  DPPADD(acc[4], acc[6], 0x4E);
  DPPADD(acc[0], acc[4], 0x141);
  DPPADD(acc[0], acc[0], 0x128);
  acc[0] += __shfl_xor(acc[0], 16, 64);
  acc[0] += __shfl_xor(acc[0], 32, 64);
  if (lane < 8) y[(size_t)(g * 8 + lane) * EE + r] = acc[0] + bias[r];
}

extern "C" void kernel_launch(void* const* d_in, const int* in_sizes, int n_in,
                              void* d_out, int out_size, void* d_ws, size_t ws_size,
                              hipStream_t stream) {
  const float* src = (const float*)d_in[0];
  const float* Wq  = (const float*)d_in[1];
  const float* bq  = (const float*)d_in[2];
  const float* Wk  = (const float*)d_in[3];
  const float* Wv  = (const float*)d_in[5];
  const float* bv  = (const float*)d_in[6];
  const float* Wo  = (const float*)d_in[7];
  const float* bo  = (const float*)d_in[8];
  const float* Wl  = (const float*)d_in[9];
  const float* bl  = (const float*)d_in[10];
  float* out = (float*)d_out;

  float* ws = (float*)d_ws;
  float* qk   = ws;                               // 131072
  float* lw   = qk + 131072;                      // 512*8 = 4096
  float* ctx  = lw + 4096;                        // 131072
  float* vout = ctx + 131072;                     // 16384
  float* y1   = vout + 16384;                     // 16384
  float* part = y1 + 16384;                       // 512*4096 floats (8MB)

  k_qproj<<<256, 256, 0, stream>>>(src, Wq, bq, Wk, qk);
  k_fused<<<NB * NCHUNK, 256, 0, stream>>>(src, qk, part, lw);
  k_combine<<<512, 256, 0, stream>>>(part, lw, ctx);
  k_gemv<1><<<2048, 64, 0, stream>>>(ctx, Wv, bv, vout);
  k_gemv<0><<<2048, 64, 0, stream>>>(vout, Wo, bo, y1);
  k_gemv<0><<<2048, 64, 0, stream>>>(y1, Wl, bl, out);
}